// Round 13
// baseline (317.320 us; speedup 1.0000x reference)
//
#include <hip/hip_runtime.h>
#include <hip/hip_fp16.h>

// Problem constants (match reference setup_inputs)
#define NN 200000   // nodes
#define RR 4        // relations
#define EE 1000000  // edges per relation
#define BB 1024     // graphs
#define RN (RR*NN)  // 800000

#define BSH 7                         // fine bucket shift -> 128 nodes/bucket
#define BSZ 128                       // nodes per fine bucket
#define NB 1563                       // ceil(NN/128)
#define RK (RR*NB)                    // 6252
#define CSH 10                        // coarse shift -> 1024 nodes/coarse bucket
#define CNODES 1024
#define CC 196                        // ceil(NN/1024)
#define EPB 4096                      // edges per partition tile (fits LDS radix stage)
#define SBT 1024                      // partition block threads
#define BPR ((EE + EPB - 1) / EPB)    // 245 blocks per relation
#define GSLOTS 32                     // per-block graph slots for pooling
#define STG 6144                      // k_fineD LDS record staging (mean 5120, +14 sigma)

// compact record layout (k_l2): dl(0-6) | src(7-24) | deg(25-30)
#define SRC_OF(u)  (((u) >> 7) & 0x3FFFF)
#define DL_OF(u)   ((int)((u) & 127))
#define DEG_OF(u)  ((u) >> 25)

// ---------------- workspace layout (4-byte units) ----------------
// Exact-sized pipeline: counts -> scan -> bases; no capacity slack anywhere.
#define OFF_POOL    0                         // f[BB*16]
#define OFF_CNT     (OFF_POOL + BB*16)        // f[BB]
#define OFF_CNTS    (OFF_CNT + BB)            // int[RR*CC] coarse src counts
#define OFF_CNTD    (OFF_CNTS + RR*CC)        // int[RR*CC] coarse dst counts
#define OFF_CURS    (OFF_CNTD + RR*CC)        // int[RR*CC] src scatter cursors
#define OFF_CURD    (OFF_CURS + RR*CC)        // int[RR*CC] dst scatter cursors
#define OFF_GSB     (OFF_CURD + RR*CC)        // int[RR*CC+1] exact src bases
#define OFF_GDB     (OFF_GSB + RR*CC + 1)     // int[RR*CC+1] exact dst bases
#define OFF_GFIN    (OFF_GDB + RR*CC + 1)     // int[RK+1] exact fine-bin bases into kw4
#define OFF_PBCS    (OFF_GFIN + RK + 1)       // int[BPR*RR*CC] per-block src counts
#define OFF_PBCD    (OFF_PBCS + BPR*RR*CC)    // int[BPR*RR*CC] per-block dst counts
#define ZERO_UNITS_ (OFF_PBCD + BPR*RR*CC)
#define ZERO_UNITS  (ZERO_UNITS_ + (ZERO_UNITS_ & 1))  // ~1.6 MB zeroed, even
#define OFF_DEGB    ZERO_UNITS                // uchar[RN] out-deg (clamped 1..63)
#define OFF_INVI    (OFF_DEGB + RN/4)         // f[RN] rsqrt(in_deg)
#define OFF_RW16    (OFF_INVI + RN)           // ushort[RN] node run start within fine bin
#define OFF_AGG1    (OFF_RW16 + RN/2)         // f[RN*2]
#define OFF_SBC     OFF_AGG1                  // ushort[RR*EE] src coarse bins; ALIASES
                                              // agg1+h1h head (dead before they're written)
#define OFF_H1H     (OFF_AGG1 + RN*2)         // half[NN*16] = NN*8 units
#define OFF_KWC_    (OFF_H1H + NN*8)
#define OFF_KWC     (OFF_KWC_ + (OFF_KWC_ & 1)) // ulonglong[RR*EE] merged 8B records
#define OFF_KW4     (OFF_KWC + RR*EE*2)       // uint[RR*EE] compact node-sorted records
// total ~= 64.6 MiB

// ---------------- kernels ----------------

// Pass 0: exact coarse-bucket counts via LDS histograms. int4 loads.
// Persists per-(block,relation,bucket) counts for k_part (same EPB tiling).
__global__ __launch_bounds__(1024) void k_cnt(const int* __restrict__ src,
                                              const int* __restrict__ dst,
                                              int* __restrict__ cntS,
                                              int* __restrict__ cntD,
                                              int* __restrict__ pbcS,
                                              int* __restrict__ pbcD) {
  __shared__ int hS[CC], hD[CC];
  int t = threadIdx.x, r = blockIdx.y, c0 = blockIdx.x * EPB;
  if (t < CC) { hS[t] = 0; hD[t] = 0; }
  __syncthreads();
  const int4* s4p = (const int4*)(src + (size_t)r * EE + c0);
  const int4* d4p = (const int4*)(dst + (size_t)r * EE + c0);
  int nv = min(EPB, EE - c0) >> 2;     // tile size always divisible by 4
  for (int i = t; i < nv; i += 1024) {
    int4 s = s4p[i], d = d4p[i];
    atomicAdd(&hS[s.x >> CSH], 1); atomicAdd(&hS[s.y >> CSH], 1);
    atomicAdd(&hS[s.z >> CSH], 1); atomicAdd(&hS[s.w >> CSH], 1);
    atomicAdd(&hD[d.x >> CSH], 1); atomicAdd(&hD[d.y >> CSH], 1);
    atomicAdd(&hD[d.z >> CSH], 1); atomicAdd(&hD[d.w >> CSH], 1);
  }
  __syncthreads();
  if (t < CC) {
    size_t pb = (size_t)(blockIdx.x * RR + r) * CC + t;
    pbcS[pb] = hS[t];
    pbcD[pb] = hD[t];
    if (hS[t]) atomicAdd(&cntS[r * CC + t], hS[t]);
    if (hD[t]) atomicAdd(&cntD[r * CC + t], hD[t]);
  }
}

// Pass 0b: segmented exclusive scan (per relation) of counts -> exact bases.
__global__ __launch_bounds__(1024) void k_scan(const int* __restrict__ cntS,
                                               const int* __restrict__ cntD,
                                               int* __restrict__ gsb,
                                               int* __restrict__ gdb,
                                               int* __restrict__ gfin) {
  __shared__ int s[1024];
  int t = threadIdx.x;
  // src side
  int v = (t < RR * CC) ? cntS[t] : 0;
  s[t] = v;
  __syncthreads();
  for (int off = 1; off < 1024; off <<= 1) {
    int u = (t >= off) ? s[t - off] : 0;
    __syncthreads();
    s[t] += u;
    __syncthreads();
  }
  if (t < RR * CC) {
    int r = t / CC;
    int pre = (r == 0) ? 0 : s[r * CC - 1];
    gsb[t] = r * EE + (s[t] - v) - pre;
  }
  if (t == 0) gsb[RR * CC] = RR * EE;
  __syncthreads();
  // dst side
  int w = (t < RR * CC) ? cntD[t] : 0;
  s[t] = w;
  __syncthreads();
  for (int off = 1; off < 1024; off <<= 1) {
    int u = (t >= off) ? s[t - off] : 0;
    __syncthreads();
    s[t] += u;
    __syncthreads();
  }
  if (t < RR * CC) {
    int r = t / CC;
    int pre = (r == 0) ? 0 : s[r * CC - 1];
    gdb[t] = r * EE + (s[t] - w) - pre;
  }
  if (t == 0) { gdb[RR * CC] = RR * EE; gfin[RK] = RR * EE; }
}

// Pass A: LDS-STAGED RADIX SCATTER. Per tile: local offsets from pbc counts,
// scatter records into bucket-sorted LDS (32 KB rec + 8 KB src-local), then
// linear sweep writes LDS->global COALESCED (consecutive threads, consecutive
// addresses; bucket via 8-step binary search). Converts ~64-line wave-stores
// into 1-2-line wave-stores. Record: {ew_h16 | src18<<10 | dcl10}.
__global__ __launch_bounds__(SBT) void k_part(const int* __restrict__ src,
                                              const int* __restrict__ dst,
                                              const float* __restrict__ ew,
                                              const int* __restrict__ gsb,
                                              const int* __restrict__ gdb,
                                              const int* __restrict__ pbcS,
                                              const int* __restrict__ pbcD,
                                              int* __restrict__ curS,
                                              int* __restrict__ curD,
                                              unsigned short* __restrict__ sbc,
                                              unsigned long long* __restrict__ kwc) {
  __shared__ unsigned long long rbuf[EPB];   // 32 KB bucket-sorted records
  __shared__ unsigned short sbuf[EPB];       // 8 KB bucket-sorted src-locals
  __shared__ int s4[1024];                   // scan temp
  __shared__ int ofS[CC + 1], ofD[CC + 1];   // local exclusive offsets
  __shared__ int bS[CC], bD[CC];             // global bases for this block
  __shared__ int lS[CC], lD[CC];             // LDS scatter cursors
  int t = threadIdx.x, r = blockIdx.y, c0 = blockIdx.x * EPB;
  int ne = min(EPB, EE - c0);
  int vS = 0, vD = 0;
  if (t < CC) {
    size_t pb = (size_t)(blockIdx.x * RR + r) * CC + t;
    int kc = r * CC + t;
    vS = pbcS[pb];
    vD = pbcD[pb];
    bS[t] = vS ? gsb[kc] + atomicAdd(&curS[kc], vS) : 0;
    bD[t] = vD ? gdb[kc] + atomicAdd(&curD[kc], vD) : 0;
    lS[t] = 0; lD[t] = 0;
  }
  // local exclusive scan of S counts
  s4[t] = (t < CC) ? vS : 0;
  __syncthreads();
  for (int off = 1; off < 1024; off <<= 1) {
    int u = (t >= off) ? s4[t - off] : 0;
    __syncthreads();
    s4[t] += u;
    __syncthreads();
  }
  if (t < CC) ofS[t] = s4[t] - vS;
  if (t == 0) ofS[CC] = ne;
  __syncthreads();
  // local exclusive scan of D counts
  s4[t] = (t < CC) ? vD : 0;
  __syncthreads();
  for (int off = 1; off < 1024; off <<= 1) {
    int u = (t >= off) ? s4[t - off] : 0;
    __syncthreads();
    s4[t] += u;
    __syncthreads();
  }
  if (t < CC) ofD[t] = s4[t] - vD;
  if (t == 0) ofD[CC] = ne;
  __syncthreads();
  // scatter into LDS (vectorized reads)
  const int4*   s4p = (const int4*)  (src + (size_t)r * EE + c0);
  const int4*   d4p = (const int4*)  (dst + (size_t)r * EE + c0);
  const float4* e4p = (const float4*)(ew  + (size_t)r * EE + c0);
  int nv = ne >> 2;
  for (int i = t; i < nv; i += SBT) {
    int4 sv = s4p[i], dv = d4p[i];
    float4 wv = e4p[i];
    int ss[4] = {sv.x, sv.y, sv.z, sv.w};
    int dd[4] = {dv.x, dv.y, dv.z, dv.w};
    float we[4] = {wv.x, wv.y, wv.z, wv.w};
#pragma unroll
    for (int j = 0; j < 4; j++) {
      int s = ss[j], d = dd[j];
      int cs = s >> CSH;
      int ps = atomicAdd(&lS[cs], 1);
      sbuf[ofS[cs] + ps] = (unsigned short)(s & (CNODES - 1));
      int cd = d >> CSH;
      int pd = atomicAdd(&lD[cd], 1);
      unsigned low = (unsigned)(d & (CNODES - 1)) | ((unsigned)s << CSH);
      rbuf[ofD[cd] + pd] =
          ((unsigned long long)__half_as_ushort(__float2half_rn(we[j])) << 32) | low;
    }
  }
  __syncthreads();
  // coalesced write-out: D records
  for (int i = t; i < ne; i += SBT) {
    int lo = 0, hi = CC;
    while (hi - lo > 1) { int mid = (lo + hi) >> 1; if (ofD[mid] <= i) lo = mid; else hi = mid; }
    kwc[(size_t)bD[lo] + (i - ofD[lo])] = rbuf[i];
  }
  // coalesced write-out: S locals
  for (int i = t; i < ne; i += SBT) {
    int lo = 0, hi = CC;
    while (hi - lo > 1) { int mid = (lo + hi) >> 1; if (ofS[mid] <= i) lo = mid; else hi = mid; }
    sbc[(size_t)bS[lo] + (i - ofS[lo])] = sbuf[i];
  }
}

// Pass B1: out-degree per (coarse bucket, relation). uint-pair (2x ushort) loads.
__global__ __launch_bounds__(1024) void k_fineS(const unsigned short* __restrict__ sbc,
                                                const int* __restrict__ gsb,
                                                unsigned char* __restrict__ degb) {
  __shared__ int h[CNODES];     // 4 KB
  int t = threadIdx.x, c = blockIdx.x, r = blockIdx.y;
  int kc = r * CC + c;
  int s0 = gsb[kc];
  int m = gsb[kc + 1] - s0;
  h[t] = 0;
  __syncthreads();
  int head = (s0 & 1) && (m > 0) ? 1 : 0;
  if (head && t == 0) atomicAdd(&h[sbc[s0]], 1);
  int mv = (m - head) >> 1;
  const unsigned* p = (const unsigned*)(sbc + s0 + head);
  for (int i = t; i < mv; i += 1024) {
    unsigned v = p[i];
    atomicAdd(&h[v & 0xFFFF], 1);
    atomicAdd(&h[v >> 16], 1);
  }
  if (((m - head) & 1) && t == 1023) atomicAdd(&h[sbc[(size_t)s0 + m - 1]], 1);
  __syncthreads();
  int n = c * CNODES + t;
  if (n < NN) degb[r * NN + n] = (unsigned char)min(max(h[t], 1), 63);
}

// Pass B2: per (coarse bucket, relation). Records STAGED ONCE in LDS (48 KB,
// global fallback for rare >STG tail); histogram + scan -> invi/rw16/gfin;
// single sweep: gather degb (L2) + feat (L2/L3), accumulate layer-1 aggregate
// in 8 KB LDS, scatter 4B compact node-sorted record at exact positions.
__global__ __launch_bounds__(1024) void k_fineD(const unsigned long long* __restrict__ kwc,
                                                const int* __restrict__ gdb,
                                                const unsigned char* __restrict__ degb,
                                                const float* __restrict__ feat,
                                                unsigned* __restrict__ kw4,
                                                int* __restrict__ gfin,
                                                float* __restrict__ invi,
                                                unsigned short* __restrict__ rw16,
                                                float* __restrict__ agg1) {
  __shared__ unsigned long long buf[STG]; // 48 KB staged records
  __shared__ int h[CNODES];        // 4 KB: counts -> cursors
  __shared__ float la[CNODES * 2]; // 8 KB: layer-1 aggregate
  __shared__ int s4[1024];         // block scan
  __shared__ int sfb[8];           // fine-bin base offsets within bucket
  int t = threadIdx.x, c = blockIdx.x, r = blockIdx.y;
  int kc = r * CC + c;
  int b0 = gdb[kc];
  int nrec = gdb[kc + 1] - b0;
  int stg = min(nrec, STG);
  h[t] = 0; la[t] = 0.f; la[t + CNODES] = 0.f;
  for (int i = t; i < stg; i += 1024) buf[i] = kwc[(size_t)b0 + i];
  __syncthreads();
  for (int i = t; i < nrec; i += 1024) {
    unsigned low = (unsigned)((i < STG) ? buf[i] : kwc[(size_t)b0 + i]);
    atomicAdd(&h[low & (CNODES - 1)], 1);
  }
  __syncthreads();
  int cntt = h[t];
  s4[t] = cntt;
  __syncthreads();
  for (int off = 1; off < 1024; off <<= 1) {
    int v = (t >= off) ? s4[t - off] : 0;
    __syncthreads();
    s4[t] += v;
    __syncthreads();
  }
  int base = s4[t] - cntt;                // exclusive within bucket
  if ((t & 127) == 0) sfb[t >> 7] = base;
  __syncthreads();
  int n0 = c * CNODES;
  {
    int n = n0 + t;
    if (n < NN) {
      invi[r * NN + n] = rsqrtf((float)max(cntt, 1));
      rw16[r * NN + n] = (unsigned short)(base - sfb[t >> 7]);
    }
  }
  if (t < 8) {
    int kb = c * 8 + t;
    if (kb < NB) gfin[r * NB + kb] = b0 + sfb[t];
  }
  __syncthreads();
  h[t] = base;                            // counts -> cursors
  __syncthreads();
  // main sweep: layer-1 aggregate in LDS + compact node-sorted record
  for (int i = t; i < nrec; i += 1024) {
    unsigned long long rc = (i < STG) ? buf[i] : kwc[(size_t)b0 + i];
    unsigned low = (unsigned)rc;
    int dcl = low & (CNODES - 1);
    int s = low >> CSH;
    float ewf = __half2float(__ushort_as_half((unsigned short)(rc >> 32)));
    unsigned dg = degb[r * NN + s];
    float w1 = ewf * rsqrtf((float)dg);
    float2 fv = ((const float2*)feat)[s];
    atomicAdd(&la[dcl * 2],     fv.x * w1);
    atomicAdd(&la[dcl * 2 + 1], fv.y * w1);
    int pos = atomicAdd(&h[dcl], 1);
    kw4[(size_t)b0 + pos] = ((unsigned)dcl & 127u) | ((unsigned)s << 7) | (dg << 25);
  }
  __syncthreads();
  {
    int n = n0 + t;
    if (n < NN)
      ((float2*)agg1)[r * NN + n] = make_float2(la[t * 2], la[t * 2 + 1]);
  }
}

__device__ __forceinline__ unsigned pack2h(float a, float b) {
  __half2 h = __floats2half2_rn(a, b);
  return *reinterpret_cast<unsigned*>(&h);
}

// Layer-1 transform: h1h (fp16) = relu(sum_r invi*agg1[r] @ W1[r] + sum_r b1[r]).
__global__ __launch_bounds__(256) void k_l1b(const float* __restrict__ agg1,
                                             const float* __restrict__ invi,
                                             const float* __restrict__ W1,
                                             const float* __restrict__ b1,
                                             __half* __restrict__ h1h) {
  __shared__ float sW[RR * 2 * 16];
  __shared__ float sb[16];
  int t = threadIdx.x, b = blockIdx.x;
  if (t < RR * 2 * 16) sW[t] = W1[t];
  if (t < 16) {
    float s = 0.f;
    for (int r = 0; r < RR; r++) s += b1[r * 16 + t];
    sb[t] = s;
  }
  __syncthreads();
  int n = b * 256 + t;
  if (n >= NN) return;
  float acc[16];
#pragma unroll
  for (int j = 0; j < 16; j++) acc[j] = sb[j];
#pragma unroll
  for (int r = 0; r < RR; r++) {
    float iv = invi[r * NN + n];
    float2 a = ((const float2*)agg1)[r * NN + n];
    float a0 = a.x * iv, a1 = a.y * iv;
#pragma unroll
    for (int j = 0; j < 16; j++)
      acc[j] += a0 * sW[(r * 2 + 0) * 16 + j] + a1 * sW[(r * 2 + 1) * 16 + j];
  }
#pragma unroll
  for (int j = 0; j < 16; j++) acc[j] = fmaxf(acc[j], 0.f);
  uint4 u0, u1;
  u0.x = pack2h(acc[0], acc[1]);  u0.y = pack2h(acc[2], acc[3]);
  u0.z = pack2h(acc[4], acc[5]);  u0.w = pack2h(acc[6], acc[7]);
  u1.x = pack2h(acc[8], acc[9]);  u1.y = pack2h(acc[10], acc[11]);
  u1.z = pack2h(acc[12], acc[13]); u1.w = pack2h(acc[14], acc[15]);
  uint4* o = (uint4*)(h1h + (size_t)n * 16);
  o[0] = u0; o[1] = u1;
}

__device__ __forceinline__ void acc8(float* acc, uint4 u, float w) {
  float2 p;
  p = __half22float2(*(__half2*)&u.x); acc[0] += p.x * w; acc[1] += p.y * w;
  p = __half22float2(*(__half2*)&u.y); acc[2] += p.x * w; acc[3] += p.y * w;
  p = __half22float2(*(__half2*)&u.z); acc[4] += p.x * w; acc[5] += p.y * w;
  p = __half22float2(*(__half2*)&u.w); acc[6] += p.x * w; acc[7] += p.y * w;
}

// Layer-2 per fine bin, FUSED over relations (round-9 proven version): per r
// {batched 4-deep run-walk, W2-fold into out[16]}, then ONE pooling phase.
__global__ __launch_bounds__(256) void k_l2(const unsigned* __restrict__ kw4,
                                            const int* __restrict__ gfin,
                                            const unsigned short* __restrict__ rw16,
                                            const __half* __restrict__ h1h,
                                            const float* __restrict__ invi,
                                            const float* __restrict__ W2,
                                            const int* __restrict__ gid,
                                            float* __restrict__ pool,
                                            float* __restrict__ cnt) {
  __shared__ float agg[BSZ * 17];      // 8.7 KB (overwritten each r)
  __shared__ float sW4[RR * 256];      // 4 KB: all 4 relations' W2
  __shared__ int   sg[BSZ];
  __shared__ unsigned short srw[BSZ + 2];
  __shared__ float gslot[GSLOTS * 16];
  __shared__ int   cslot[GSLOTS];
  __shared__ int   present[GSLOTS];
  int t = threadIdx.x, b = blockIdx.x;
  int n0 = b << BSH;
#pragma unroll
  for (int r = 0; r < RR; r++) sW4[r * 256 + t] = W2[r * 256 + t];
  if (t < GSLOTS) { cslot[t] = 0; present[t] = 0; }
  for (int i = t; i < GSLOTS * 16; i += 256) gslot[i] = 0.f;
  int n = n0 + t;
  bool valid = (t < BSZ) && (n < NN);
  float out[16];
#pragma unroll
  for (int j = 0; j < 16; j++) out[j] = 0.f;
  const uint4* h4p = (const uint4*)h1h;          // 2 x 16 B per node row
  int f8 = t & 1, g = t >> 1;                    // 128 groups of 2 lanes

  for (int r = 0; r < RR; r++) {
    int k = r * NB + b;
    int base = gfin[k];
    int m = gfin[k + 1] - base;
    __syncthreads();                             // protect srw/agg reuse
    if (t < BSZ) {
      int nn_ = n0 + t;
      srw[t] = (nn_ < NN) ? rw16[r * NN + nn_] : (unsigned short)m;
    }
    if (t == BSZ) srw[BSZ] = (unsigned short)m;
    __syncthreads();
    const unsigned* rb = kw4 + (size_t)base;
    int e = srw[g], en = srw[g + 1];
    float acc[8];
#pragma unroll
    for (int j = 0; j < 8; j++) acc[j] = 0.f;
    for (; e + 3 < en; e += 4) {                 // 4 independent gather chains
      unsigned r0 = rb[e], r1 = rb[e + 1], r2 = rb[e + 2], r3 = rb[e + 3];
      uint4 u0 = h4p[(size_t)SRC_OF(r0) * 2 + f8];
      uint4 u1 = h4p[(size_t)SRC_OF(r1) * 2 + f8];
      uint4 u2 = h4p[(size_t)SRC_OF(r2) * 2 + f8];
      uint4 u3 = h4p[(size_t)SRC_OF(r3) * 2 + f8];
      acc8(acc, u0, rsqrtf((float)DEG_OF(r0)));
      acc8(acc, u1, rsqrtf((float)DEG_OF(r1)));
      acc8(acc, u2, rsqrtf((float)DEG_OF(r2)));
      acc8(acc, u3, rsqrtf((float)DEG_OF(r3)));
    }
    for (; e < en; e++) {
      unsigned rr = rb[e];
      uint4 u = h4p[(size_t)SRC_OF(rr) * 2 + f8];
      acc8(acc, u, rsqrtf((float)DEG_OF(rr)));
    }
#pragma unroll
    for (int j = 0; j < 8; j++) agg[g * 17 + 8 * f8 + j] = acc[j];
    __syncthreads();
    if (valid) {
      float iv = invi[r * NN + n];
#pragma unroll
      for (int kk = 0; kk < 16; kk++) {
        float a = agg[t * 17 + kk] * iv;
#pragma unroll
        for (int j = 0; j < 16; j++) out[j] += a * sW4[r * 256 + kk * 16 + j];
      }
    }
  }
  __syncthreads();
  int g0 = gid[n0];
  if (t < BSZ) {
    sg[t] = valid ? (gid[n] - g0) : -1;
#pragma unroll
    for (int j = 0; j < 16; j++) agg[t * 17 + j] = out[j];  // own row only
  }
  __syncthreads();
  // parallel pooling into per-graph slots (ONCE, summed over relations)
  {
    int f = t & 15, i0 = t >> 4;
    for (int i = i0; i < BSZ; i += 16) {
      int gsN = sg[i];
      if (gsN < 0) continue;
      float v = agg[i * 17 + f];
      if (gsN < GSLOTS) {
        atomicAdd(&gslot[gsN * 16 + f], v);
        if (f == 0) {
          present[gsN] = 1;
          atomicAdd(&cslot[gsN], 1);
        }
      } else {  // overflow fallback (practically never)
        atomicAdd(&pool[(g0 + gsN) * 16 + f], v);
        if (f == 0) atomicAdd(&cnt[g0 + gsN], 1.0f);
      }
    }
  }
  __syncthreads();
  if (t < GSLOTS * 16) {
    int gsN = t >> 4, f = t & 15;
    if (present[gsN]) atomicAdd(&pool[(g0 + gsN) * 16 + f], gslot[t]);
  }
  if (t < GSLOTS && cslot[t] > 0)
    atomicAdd(&cnt[g0 + t], (float)cslot[t]);
}

// Head: v = (pool + cnt*sum_r b2)/max(cnt,1); out = v @ Wc + bc.
__global__ __launch_bounds__(256) void k_final(const float* __restrict__ pool,
                                               const float* __restrict__ cnt,
                                               const float* __restrict__ b2,
                                               const float* __restrict__ Wc,
                                               const float* __restrict__ bc,
                                               float* __restrict__ out) {
  int b = blockIdx.x * 256 + threadIdx.x;
  if (b >= BB) return;
  float c = cnt[b];
  float inv = 1.0f / fmaxf(c, 1.0f);
  float o0 = bc[0], o1 = bc[1];
#pragma unroll
  for (int j = 0; j < 16; j++) {
    float sb = 0.f;
    for (int r = 0; r < RR; r++) sb += b2[r * 16 + j];
    float v = (pool[b * 16 + j] + c * sb) * inv;
    o0 += v * Wc[j * 2 + 0];
    o1 += v * Wc[j * 2 + 1];
  }
  out[b * 2 + 0] = o0;
  out[b * 2 + 1] = o1;
}

extern "C" void kernel_launch(void* const* d_in, const int* in_sizes, int n_in,
                              void* d_out, int out_size, void* d_ws, size_t ws_size,
                              hipStream_t stream) {
  const float* feat = (const float*)d_in[0];
  const int*   src  = (const int*)d_in[1];
  const int*   dst  = (const int*)d_in[2];
  const float* ew   = (const float*)d_in[3];
  const int*   gid  = (const int*)d_in[4];
  const float* W1   = (const float*)d_in[5];
  const float* b1   = (const float*)d_in[6];
  const float* W2   = (const float*)d_in[7];
  const float* b2   = (const float*)d_in[8];
  const float* Wc   = (const float*)d_in[9];
  const float* bc   = (const float*)d_in[10];

  char* ws = (char*)d_ws;
  float* pool   = (float*)(ws + (size_t)OFF_POOL * 4);
  float* cnt    = (float*)(ws + (size_t)OFF_CNT  * 4);
  int*   cntS   = (int*)  (ws + (size_t)OFF_CNTS * 4);
  int*   cntD   = (int*)  (ws + (size_t)OFF_CNTD * 4);
  int*   curS   = (int*)  (ws + (size_t)OFF_CURS * 4);
  int*   curD   = (int*)  (ws + (size_t)OFF_CURD * 4);
  int*   gsb    = (int*)  (ws + (size_t)OFF_GSB  * 4);
  int*   gdb    = (int*)  (ws + (size_t)OFF_GDB  * 4);
  int*   gfin   = (int*)  (ws + (size_t)OFF_GFIN * 4);
  int*   pbcS   = (int*)  (ws + (size_t)OFF_PBCS * 4);
  int*   pbcD   = (int*)  (ws + (size_t)OFF_PBCD * 4);
  unsigned char*  degb = (unsigned char*) (ws + (size_t)OFF_DEGB * 4);
  float* invi   = (float*)(ws + (size_t)OFF_INVI * 4);
  unsigned short* rw16 = (unsigned short*)(ws + (size_t)OFF_RW16 * 4);
  float* agg1   = (float*)(ws + (size_t)OFF_AGG1 * 4);
  unsigned short* sbc  = (unsigned short*)(ws + (size_t)OFF_SBC * 4);  // alias agg1/h1h
  __half* h1h   = (__half*)(ws + (size_t)OFF_H1H * 4);
  unsigned long long* kwc = (unsigned long long*)(ws + (size_t)OFF_KWC * 4);
  unsigned* kw4 = (unsigned*)(ws + (size_t)OFF_KW4 * 4);

  hipMemsetAsync(d_ws, 0, (size_t)ZERO_UNITS * 4, stream);

  k_cnt   <<<dim3(BPR, RR), 1024, 0, stream>>>(src, dst, cntS, cntD, pbcS, pbcD);
  k_scan  <<<1, 1024, 0, stream>>>(cntS, cntD, gsb, gdb, gfin);
  k_part  <<<dim3(BPR, RR), SBT, 0, stream>>>(src, dst, ew, gsb, gdb, pbcS, pbcD,
                                              curS, curD, sbc, kwc);
  k_fineS <<<dim3(CC, RR), 1024, 0, stream>>>(sbc, gsb, degb);
  k_fineD <<<dim3(CC, RR), 1024, 0, stream>>>(kwc, gdb, degb, feat, kw4, gfin, invi, rw16, agg1);
  k_l1b   <<<(NN + 255) / 256, 256, 0, stream>>>(agg1, invi, W1, b1, h1h);
  k_l2    <<<NB, 256, 0, stream>>>(kw4, gfin, rw16, h1h, invi, W2, gid, pool, cnt);
  k_final <<<(BB + 255) / 256, 256, 0, stream>>>(pool, cnt, b2, Wc, bc, (float*)d_out);
}

// Round 14
// 303.789 us; speedup vs baseline: 1.0445x; 1.0445x over previous
//
#include <hip/hip_runtime.h>
#include <hip/hip_fp16.h>

// Problem constants (match reference setup_inputs)
#define NN 200000   // nodes
#define RR 4        // relations
#define EE 1000000  // edges per relation
#define BB 1024     // graphs
#define RN (RR*NN)  // 800000

#define BSH 7                         // fine bucket shift -> 128 nodes/bucket
#define BSZ 128                       // nodes per fine bucket
#define NB 1563                       // ceil(NN/128)
#define RK (RR*NB)                    // 6252
#define CSH 10                        // coarse shift -> 1024 nodes/coarse bucket
#define CNODES 1024
#define CC 196                        // ceil(NN/1024)
#define EPB 16384                     // edges per partition block (longer bin runs)
#define SBT 1024                      // partition block threads
#define BPR ((EE + EPB - 1) / EPB)    // 62 blocks per relation
#define GSLOTS 32                     // per-block graph slots for pooling
#define STG 6144                      // k_fineD LDS record staging (mean 5120, +14 sigma)

// compact record layout (k_l2): dl(0-6) | src(7-24) | deg(25-30)
#define SRC_OF(u)  (((u) >> 7) & 0x3FFFF)
#define DL_OF(u)   ((int)((u) & 127))
#define DEG_OF(u)  ((u) >> 25)

// ---------------- workspace layout (4-byte units) ----------------
// Exact-sized pipeline: counts -> scan -> bases; no capacity slack anywhere.
// Zeroed prefix holds ONLY buffers that need zeroing (pool/cnt/counts/cursors);
// pbc arrays are fully overwritten by k_cnt before use -> outside the prefix.
#define OFF_POOL    0                         // f[BB*16]
#define OFF_CNT     (OFF_POOL + BB*16)        // f[BB]
#define OFF_CNTS    (OFF_CNT + BB)            // int[RR*CC] coarse src counts
#define OFF_CNTD    (OFF_CNTS + RR*CC)        // int[RR*CC] coarse dst counts
#define OFF_CURS    (OFF_CNTD + RR*CC)        // int[RR*CC] src scatter cursors
#define OFF_CURD    (OFF_CURS + RR*CC)        // int[RR*CC] dst scatter cursors
#define OFF_GSB     (OFF_CURD + RR*CC)        // int[RR*CC+1] exact src bases
#define OFF_GDB     (OFF_GSB + RR*CC + 1)     // int[RR*CC+1] exact dst bases
#define OFF_GFIN    (OFF_GDB + RR*CC + 1)     // int[RK+1] exact fine-bin bases into kw4
#define ZERO_UNITS_ (OFF_GFIN + RK + 1)
#define ZERO_UNITS  (ZERO_UNITS_ + (ZERO_UNITS_ & 1))  // ~111 KB zeroed, even
#define OFF_PBCS    ZERO_UNITS                // int[BPR*RR*CC] per-block src counts (no zero)
#define OFF_PBCD    (OFF_PBCS + BPR*RR*CC)    // int[BPR*RR*CC] per-block dst counts (no zero)
#define OFF_DEGB    (OFF_PBCD + BPR*RR*CC)    // uchar[RN] out-deg (clamped 1..63)
#define OFF_INVI    (OFF_DEGB + RN/4)         // f[RN] rsqrt(in_deg)
#define OFF_RW16    (OFF_INVI + RN)           // ushort[RN] node run start within fine bin
#define OFF_AGG1    (OFF_RW16 + RN/2)         // f[RN*2]
#define OFF_SBC     OFF_AGG1                  // ushort[RR*EE] src coarse bins; ALIASES
                                              // agg1+h1h head (dead before they're written)
#define OFF_H1H     (OFF_AGG1 + RN*2)         // half[NN*16] = NN*8 units
#define OFF_KWC_    (OFF_H1H + NN*8)
#define OFF_KWC     (OFF_KWC_ + (OFF_KWC_ & 1)) // ulonglong[RR*EE] merged 8B records
#define OFF_KW4     (OFF_KWC + RR*EE*2)       // uint[RR*EE] compact node-sorted records
// total ~= 64 MiB

// ---------------- kernels ----------------

// Pass 0: exact coarse-bucket counts via LDS histograms. int4 loads.
// Persists per-(block,relation,bucket) counts so k_part skips its count phase.
__global__ __launch_bounds__(1024) void k_cnt(const int* __restrict__ src,
                                              const int* __restrict__ dst,
                                              int* __restrict__ cntS,
                                              int* __restrict__ cntD,
                                              int* __restrict__ pbcS,
                                              int* __restrict__ pbcD) {
  __shared__ int hS[CC], hD[CC];
  int t = threadIdx.x, r = blockIdx.y, c0 = blockIdx.x * EPB;
  if (t < CC) { hS[t] = 0; hD[t] = 0; }
  __syncthreads();
  const int4* s4p = (const int4*)(src + (size_t)r * EE + c0);
  const int4* d4p = (const int4*)(dst + (size_t)r * EE + c0);
  int nv = min(EPB, EE - c0) >> 2;     // tile size always divisible by 4
  for (int i = t; i < nv; i += 1024) {
    int4 s = s4p[i], d = d4p[i];
    atomicAdd(&hS[s.x >> CSH], 1); atomicAdd(&hS[s.y >> CSH], 1);
    atomicAdd(&hS[s.z >> CSH], 1); atomicAdd(&hS[s.w >> CSH], 1);
    atomicAdd(&hD[d.x >> CSH], 1); atomicAdd(&hD[d.y >> CSH], 1);
    atomicAdd(&hD[d.z >> CSH], 1); atomicAdd(&hD[d.w >> CSH], 1);
  }
  __syncthreads();
  if (t < CC) {
    size_t pb = (size_t)(blockIdx.x * RR + r) * CC + t;
    pbcS[pb] = hS[t];
    pbcD[pb] = hD[t];
    if (hS[t]) atomicAdd(&cntS[r * CC + t], hS[t]);
    if (hD[t]) atomicAdd(&cntD[r * CC + t], hD[t]);
  }
}

// Pass 0b: segmented exclusive scan (per relation) of counts -> exact bases.
__global__ __launch_bounds__(1024) void k_scan(const int* __restrict__ cntS,
                                               const int* __restrict__ cntD,
                                               int* __restrict__ gsb,
                                               int* __restrict__ gdb,
                                               int* __restrict__ gfin) {
  __shared__ int s[1024];
  int t = threadIdx.x;
  // src side
  int v = (t < RR * CC) ? cntS[t] : 0;
  s[t] = v;
  __syncthreads();
  for (int off = 1; off < 1024; off <<= 1) {
    int u = (t >= off) ? s[t - off] : 0;
    __syncthreads();
    s[t] += u;
    __syncthreads();
  }
  if (t < RR * CC) {
    int r = t / CC;
    int pre = (r == 0) ? 0 : s[r * CC - 1];
    gsb[t] = r * EE + (s[t] - v) - pre;
  }
  if (t == 0) gsb[RR * CC] = RR * EE;
  __syncthreads();
  // dst side
  int w = (t < RR * CC) ? cntD[t] : 0;
  s[t] = w;
  __syncthreads();
  for (int off = 1; off < 1024; off <<= 1) {
    int u = (t >= off) ? s[t - off] : 0;
    __syncthreads();
    s[t] += u;
    __syncthreads();
  }
  if (t < RR * CC) {
    int r = t / CC;
    int pre = (r == 0) ? 0 : s[r * CC - 1];
    gdb[t] = r * EE + (s[t] - w) - pre;
  }
  if (t == 0) { gdb[RR * CC] = RR * EE; gfin[RK] = RR * EE; }
}

// Pass A: coarse partition at exact bases — SINGLE PHASE (per-block counts
// from k_cnt's pbc). dst side: ONE 8B merged record {ew_h16|src18|dcl10};
// src side: 2B local. int4/float4 loads, ~42-record near-full-line runs.
__global__ __launch_bounds__(SBT) void k_part(const int* __restrict__ src,
                                              const int* __restrict__ dst,
                                              const float* __restrict__ ew,
                                              const int* __restrict__ gsb,
                                              const int* __restrict__ gdb,
                                              const int* __restrict__ pbcS,
                                              const int* __restrict__ pbcD,
                                              int* __restrict__ curS,
                                              int* __restrict__ curD,
                                              unsigned short* __restrict__ sbc,
                                              unsigned long long* __restrict__ kwc) {
  __shared__ int bS[CC], lS[CC];
  __shared__ int bD[CC], lD[CC];
  int t = threadIdx.x, r = blockIdx.y, c0 = blockIdx.x * EPB;
  if (t < CC) {
    size_t pb = (size_t)(blockIdx.x * RR + r) * CC + t;
    int kc = r * CC + t;
    int v = pbcS[pb];
    bS[t] = v ? gsb[kc] + atomicAdd(&curS[kc], v) : 0;
    lS[t] = 0;
    int w = pbcD[pb];
    bD[t] = w ? gdb[kc] + atomicAdd(&curD[kc], w) : 0;
    lD[t] = 0;
  }
  __syncthreads();
  const int4*   s4p = (const int4*)  (src + (size_t)r * EE + c0);
  const int4*   d4p = (const int4*)  (dst + (size_t)r * EE + c0);
  const float4* e4p = (const float4*)(ew  + (size_t)r * EE + c0);
  int nv = min(EPB, EE - c0) >> 2;
  for (int i = t; i < nv; i += SBT) {
    int4 s4 = s4p[i], d4 = d4p[i];
    float4 w4 = e4p[i];
    int ss[4] = {s4.x, s4.y, s4.z, s4.w};
    int dd[4] = {d4.x, d4.y, d4.z, d4.w};
    float we[4] = {w4.x, w4.y, w4.z, w4.w};
#pragma unroll
    for (int j = 0; j < 4; j++) {
      int s = ss[j], d = dd[j];
      int cs = s >> CSH;
      sbc[(size_t)bS[cs] + atomicAdd(&lS[cs], 1)] = (unsigned short)(s & (CNODES - 1));
      int cd = d >> CSH;
      unsigned low = (unsigned)(d & (CNODES - 1)) | ((unsigned)s << CSH);
      unsigned long long rec =
          ((unsigned long long)__half_as_ushort(__float2half_rn(we[j])) << 32) | low;
      kwc[(size_t)bD[cd] + atomicAdd(&lD[cd], 1)] = rec;
    }
  }
}

// Pass B1: out-degree per (coarse bucket, relation). uint-pair (2x ushort) loads.
__global__ __launch_bounds__(1024) void k_fineS(const unsigned short* __restrict__ sbc,
                                                const int* __restrict__ gsb,
                                                unsigned char* __restrict__ degb) {
  __shared__ int h[CNODES];     // 4 KB
  int t = threadIdx.x, c = blockIdx.x, r = blockIdx.y;
  int kc = r * CC + c;
  int s0 = gsb[kc];
  int m = gsb[kc + 1] - s0;
  h[t] = 0;
  __syncthreads();
  int head = (s0 & 1) && (m > 0) ? 1 : 0;
  if (head && t == 0) atomicAdd(&h[sbc[s0]], 1);
  int mv = (m - head) >> 1;
  const unsigned* p = (const unsigned*)(sbc + s0 + head);
  for (int i = t; i < mv; i += 1024) {
    unsigned v = p[i];
    atomicAdd(&h[v & 0xFFFF], 1);
    atomicAdd(&h[v >> 16], 1);
  }
  if (((m - head) & 1) && t == 1023) atomicAdd(&h[sbc[(size_t)s0 + m - 1]], 1);
  __syncthreads();
  int n = c * CNODES + t;
  if (n < NN) degb[r * NN + n] = (unsigned char)min(max(h[t], 1), 63);
}

// Pass B2: per (coarse bucket, relation). Records STAGED ONCE in LDS (48 KB,
// global fallback for rare >STG tail); histogram + scan -> invi/rw16/gfin;
// single sweep: gather degb (L2) + feat (L2/L3), accumulate layer-1 aggregate
// in 8 KB LDS, scatter 4B compact node-sorted record at exact positions.
__global__ __launch_bounds__(1024) void k_fineD(const unsigned long long* __restrict__ kwc,
                                                const int* __restrict__ gdb,
                                                const unsigned char* __restrict__ degb,
                                                const float* __restrict__ feat,
                                                unsigned* __restrict__ kw4,
                                                int* __restrict__ gfin,
                                                float* __restrict__ invi,
                                                unsigned short* __restrict__ rw16,
                                                float* __restrict__ agg1) {
  __shared__ unsigned long long buf[STG]; // 48 KB staged records
  __shared__ int h[CNODES];        // 4 KB: counts -> cursors
  __shared__ float la[CNODES * 2]; // 8 KB: layer-1 aggregate
  __shared__ int s4[1024];         // block scan
  __shared__ int sfb[8];           // fine-bin base offsets within bucket
  int t = threadIdx.x, c = blockIdx.x, r = blockIdx.y;
  int kc = r * CC + c;
  int b0 = gdb[kc];
  int nrec = gdb[kc + 1] - b0;
  int stg = min(nrec, STG);
  h[t] = 0; la[t] = 0.f; la[t + CNODES] = 0.f;
  for (int i = t; i < stg; i += 1024) buf[i] = kwc[(size_t)b0 + i];
  __syncthreads();
  for (int i = t; i < nrec; i += 1024) {
    unsigned low = (unsigned)((i < STG) ? buf[i] : kwc[(size_t)b0 + i]);
    atomicAdd(&h[low & (CNODES - 1)], 1);
  }
  __syncthreads();
  int cntt = h[t];
  s4[t] = cntt;
  __syncthreads();
  for (int off = 1; off < 1024; off <<= 1) {
    int v = (t >= off) ? s4[t - off] : 0;
    __syncthreads();
    s4[t] += v;
    __syncthreads();
  }
  int base = s4[t] - cntt;                // exclusive within bucket
  if ((t & 127) == 0) sfb[t >> 7] = base;
  __syncthreads();
  int n0 = c * CNODES;
  {
    int n = n0 + t;
    if (n < NN) {
      invi[r * NN + n] = rsqrtf((float)max(cntt, 1));
      rw16[r * NN + n] = (unsigned short)(base - sfb[t >> 7]);
    }
  }
  if (t < 8) {
    int kb = c * 8 + t;
    if (kb < NB) gfin[r * NB + kb] = b0 + sfb[t];
  }
  __syncthreads();
  h[t] = base;                            // counts -> cursors
  __syncthreads();
  // main sweep: layer-1 aggregate in LDS + compact node-sorted record
  for (int i = t; i < nrec; i += 1024) {
    unsigned long long rc = (i < STG) ? buf[i] : kwc[(size_t)b0 + i];
    unsigned low = (unsigned)rc;
    int dcl = low & (CNODES - 1);
    int s = low >> CSH;
    float ewf = __half2float(__ushort_as_half((unsigned short)(rc >> 32)));
    unsigned dg = degb[r * NN + s];
    float w1 = ewf * rsqrtf((float)dg);
    float2 fv = ((const float2*)feat)[s];
    atomicAdd(&la[dcl * 2],     fv.x * w1);
    atomicAdd(&la[dcl * 2 + 1], fv.y * w1);
    int pos = atomicAdd(&h[dcl], 1);
    kw4[(size_t)b0 + pos] = ((unsigned)dcl & 127u) | ((unsigned)s << 7) | (dg << 25);
  }
  __syncthreads();
  {
    int n = n0 + t;
    if (n < NN)
      ((float2*)agg1)[r * NN + n] = make_float2(la[t * 2], la[t * 2 + 1]);
  }
}

__device__ __forceinline__ unsigned pack2h(float a, float b) {
  __half2 h = __floats2half2_rn(a, b);
  return *reinterpret_cast<unsigned*>(&h);
}

// Layer-1 transform: h1h (fp16) = relu(sum_r invi*agg1[r] @ W1[r] + sum_r b1[r]).
__global__ __launch_bounds__(256) void k_l1b(const float* __restrict__ agg1,
                                             const float* __restrict__ invi,
                                             const float* __restrict__ W1,
                                             const float* __restrict__ b1,
                                             __half* __restrict__ h1h) {
  __shared__ float sW[RR * 2 * 16];
  __shared__ float sb[16];
  int t = threadIdx.x, b = blockIdx.x;
  if (t < RR * 2 * 16) sW[t] = W1[t];
  if (t < 16) {
    float s = 0.f;
    for (int r = 0; r < RR; r++) s += b1[r * 16 + t];
    sb[t] = s;
  }
  __syncthreads();
  int n = b * 256 + t;
  if (n >= NN) return;
  float acc[16];
#pragma unroll
  for (int j = 0; j < 16; j++) acc[j] = sb[j];
#pragma unroll
  for (int r = 0; r < RR; r++) {
    float iv = invi[r * NN + n];
    float2 a = ((const float2*)agg1)[r * NN + n];
    float a0 = a.x * iv, a1 = a.y * iv;
#pragma unroll
    for (int j = 0; j < 16; j++)
      acc[j] += a0 * sW[(r * 2 + 0) * 16 + j] + a1 * sW[(r * 2 + 1) * 16 + j];
  }
#pragma unroll
  for (int j = 0; j < 16; j++) acc[j] = fmaxf(acc[j], 0.f);
  uint4 u0, u1;
  u0.x = pack2h(acc[0], acc[1]);  u0.y = pack2h(acc[2], acc[3]);
  u0.z = pack2h(acc[4], acc[5]);  u0.w = pack2h(acc[6], acc[7]);
  u1.x = pack2h(acc[8], acc[9]);  u1.y = pack2h(acc[10], acc[11]);
  u1.z = pack2h(acc[12], acc[13]); u1.w = pack2h(acc[14], acc[15]);
  uint4* o = (uint4*)(h1h + (size_t)n * 16);
  o[0] = u0; o[1] = u1;
}

__device__ __forceinline__ void acc8(float* acc, uint4 u, float w) {
  float2 p;
  p = __half22float2(*(__half2*)&u.x); acc[0] += p.x * w; acc[1] += p.y * w;
  p = __half22float2(*(__half2*)&u.y); acc[2] += p.x * w; acc[3] += p.y * w;
  p = __half22float2(*(__half2*)&u.z); acc[4] += p.x * w; acc[5] += p.y * w;
  p = __half22float2(*(__half2*)&u.w); acc[6] += p.x * w; acc[7] += p.y * w;
}

// Layer-2 per fine bin, FUSED over relations (round-9 proven version): per r
// {batched 4-deep run-walk, W2-fold into out[16]}, then ONE pooling phase.
__global__ __launch_bounds__(256) void k_l2(const unsigned* __restrict__ kw4,
                                            const int* __restrict__ gfin,
                                            const unsigned short* __restrict__ rw16,
                                            const __half* __restrict__ h1h,
                                            const float* __restrict__ invi,
                                            const float* __restrict__ W2,
                                            const int* __restrict__ gid,
                                            float* __restrict__ pool,
                                            float* __restrict__ cnt) {
  __shared__ float agg[BSZ * 17];      // 8.7 KB (overwritten each r)
  __shared__ float sW4[RR * 256];      // 4 KB: all 4 relations' W2
  __shared__ int   sg[BSZ];
  __shared__ unsigned short srw[BSZ + 2];
  __shared__ float gslot[GSLOTS * 16];
  __shared__ int   cslot[GSLOTS];
  __shared__ int   present[GSLOTS];
  int t = threadIdx.x, b = blockIdx.x;
  int n0 = b << BSH;
#pragma unroll
  for (int r = 0; r < RR; r++) sW4[r * 256 + t] = W2[r * 256 + t];
  if (t < GSLOTS) { cslot[t] = 0; present[t] = 0; }
  for (int i = t; i < GSLOTS * 16; i += 256) gslot[i] = 0.f;
  int n = n0 + t;
  bool valid = (t < BSZ) && (n < NN);
  float out[16];
#pragma unroll
  for (int j = 0; j < 16; j++) out[j] = 0.f;
  const uint4* h4p = (const uint4*)h1h;          // 2 x 16 B per node row
  int f8 = t & 1, g = t >> 1;                    // 128 groups of 2 lanes

  for (int r = 0; r < RR; r++) {
    int k = r * NB + b;
    int base = gfin[k];
    int m = gfin[k + 1] - base;
    __syncthreads();                             // protect srw/agg reuse
    if (t < BSZ) {
      int nn_ = n0 + t;
      srw[t] = (nn_ < NN) ? rw16[r * NN + nn_] : (unsigned short)m;
    }
    if (t == BSZ) srw[BSZ] = (unsigned short)m;
    __syncthreads();
    const unsigned* rb = kw4 + (size_t)base;
    int e = srw[g], en = srw[g + 1];
    float acc[8];
#pragma unroll
    for (int j = 0; j < 8; j++) acc[j] = 0.f;
    for (; e + 3 < en; e += 4) {                 // 4 independent gather chains
      unsigned r0 = rb[e], r1 = rb[e + 1], r2 = rb[e + 2], r3 = rb[e + 3];
      uint4 u0 = h4p[(size_t)SRC_OF(r0) * 2 + f8];
      uint4 u1 = h4p[(size_t)SRC_OF(r1) * 2 + f8];
      uint4 u2 = h4p[(size_t)SRC_OF(r2) * 2 + f8];
      uint4 u3 = h4p[(size_t)SRC_OF(r3) * 2 + f8];
      acc8(acc, u0, rsqrtf((float)DEG_OF(r0)));
      acc8(acc, u1, rsqrtf((float)DEG_OF(r1)));
      acc8(acc, u2, rsqrtf((float)DEG_OF(r2)));
      acc8(acc, u3, rsqrtf((float)DEG_OF(r3)));
    }
    for (; e < en; e++) {
      unsigned rr = rb[e];
      uint4 u = h4p[(size_t)SRC_OF(rr) * 2 + f8];
      acc8(acc, u, rsqrtf((float)DEG_OF(rr)));
    }
#pragma unroll
    for (int j = 0; j < 8; j++) agg[g * 17 + 8 * f8 + j] = acc[j];
    __syncthreads();
    if (valid) {
      float iv = invi[r * NN + n];
#pragma unroll
      for (int kk = 0; kk < 16; kk++) {
        float a = agg[t * 17 + kk] * iv;
#pragma unroll
        for (int j = 0; j < 16; j++) out[j] += a * sW4[r * 256 + kk * 16 + j];
      }
    }
  }
  __syncthreads();
  int g0 = gid[n0];
  if (t < BSZ) {
    sg[t] = valid ? (gid[n] - g0) : -1;
#pragma unroll
    for (int j = 0; j < 16; j++) agg[t * 17 + j] = out[j];  // own row only
  }
  __syncthreads();
  // parallel pooling into per-graph slots (ONCE, summed over relations)
  {
    int f = t & 15, i0 = t >> 4;
    for (int i = i0; i < BSZ; i += 16) {
      int gsN = sg[i];
      if (gsN < 0) continue;
      float v = agg[i * 17 + f];
      if (gsN < GSLOTS) {
        atomicAdd(&gslot[gsN * 16 + f], v);
        if (f == 0) {
          present[gsN] = 1;
          atomicAdd(&cslot[gsN], 1);
        }
      } else {  // overflow fallback (practically never)
        atomicAdd(&pool[(g0 + gsN) * 16 + f], v);
        if (f == 0) atomicAdd(&cnt[g0 + gsN], 1.0f);
      }
    }
  }
  __syncthreads();
  if (t < GSLOTS * 16) {
    int gsN = t >> 4, f = t & 15;
    if (present[gsN]) atomicAdd(&pool[(g0 + gsN) * 16 + f], gslot[t]);
  }
  if (t < GSLOTS && cslot[t] > 0)
    atomicAdd(&cnt[g0 + t], (float)cslot[t]);
}

// Head: v = (pool + cnt*sum_r b2)/max(cnt,1); out = v @ Wc + bc.
__global__ __launch_bounds__(256) void k_final(const float* __restrict__ pool,
                                               const float* __restrict__ cnt,
                                               const float* __restrict__ b2,
                                               const float* __restrict__ Wc,
                                               const float* __restrict__ bc,
                                               float* __restrict__ out) {
  int b = blockIdx.x * 256 + threadIdx.x;
  if (b >= BB) return;
  float c = cnt[b];
  float inv = 1.0f / fmaxf(c, 1.0f);
  float o0 = bc[0], o1 = bc[1];
#pragma unroll
  for (int j = 0; j < 16; j++) {
    float sb = 0.f;
    for (int r = 0; r < RR; r++) sb += b2[r * 16 + j];
    float v = (pool[b * 16 + j] + c * sb) * inv;
    o0 += v * Wc[j * 2 + 0];
    o1 += v * Wc[j * 2 + 1];
  }
  out[b * 2 + 0] = o0;
  out[b * 2 + 1] = o1;
}

extern "C" void kernel_launch(void* const* d_in, const int* in_sizes, int n_in,
                              void* d_out, int out_size, void* d_ws, size_t ws_size,
                              hipStream_t stream) {
  const float* feat = (const float*)d_in[0];
  const int*   src  = (const int*)d_in[1];
  const int*   dst  = (const int*)d_in[2];
  const float* ew   = (const float*)d_in[3];
  const int*   gid  = (const int*)d_in[4];
  const float* W1   = (const float*)d_in[5];
  const float* b1   = (const float*)d_in[6];
  const float* W2   = (const float*)d_in[7];
  const float* b2   = (const float*)d_in[8];
  const float* Wc   = (const float*)d_in[9];
  const float* bc   = (const float*)d_in[10];

  char* ws = (char*)d_ws;
  float* pool   = (float*)(ws + (size_t)OFF_POOL * 4);
  float* cnt    = (float*)(ws + (size_t)OFF_CNT  * 4);
  int*   cntS   = (int*)  (ws + (size_t)OFF_CNTS * 4);
  int*   cntD   = (int*)  (ws + (size_t)OFF_CNTD * 4);
  int*   curS   = (int*)  (ws + (size_t)OFF_CURS * 4);
  int*   curD   = (int*)  (ws + (size_t)OFF_CURD * 4);
  int*   gsb    = (int*)  (ws + (size_t)OFF_GSB  * 4);
  int*   gdb    = (int*)  (ws + (size_t)OFF_GDB  * 4);
  int*   gfin   = (int*)  (ws + (size_t)OFF_GFIN * 4);
  int*   pbcS   = (int*)  (ws + (size_t)OFF_PBCS * 4);
  int*   pbcD   = (int*)  (ws + (size_t)OFF_PBCD * 4);
  unsigned char*  degb = (unsigned char*) (ws + (size_t)OFF_DEGB * 4);
  float* invi   = (float*)(ws + (size_t)OFF_INVI * 4);
  unsigned short* rw16 = (unsigned short*)(ws + (size_t)OFF_RW16 * 4);
  float* agg1   = (float*)(ws + (size_t)OFF_AGG1 * 4);
  unsigned short* sbc  = (unsigned short*)(ws + (size_t)OFF_SBC * 4);  // alias agg1/h1h
  __half* h1h   = (__half*)(ws + (size_t)OFF_H1H * 4);
  unsigned long long* kwc = (unsigned long long*)(ws + (size_t)OFF_KWC * 4);
  unsigned* kw4 = (unsigned*)(ws + (size_t)OFF_KW4 * 4);

  hipMemsetAsync(d_ws, 0, (size_t)ZERO_UNITS * 4, stream);

  k_cnt   <<<dim3(BPR, RR), 1024, 0, stream>>>(src, dst, cntS, cntD, pbcS, pbcD);
  k_scan  <<<1, 1024, 0, stream>>>(cntS, cntD, gsb, gdb, gfin);
  k_part  <<<dim3(BPR, RR), SBT, 0, stream>>>(src, dst, ew, gsb, gdb, pbcS, pbcD,
                                              curS, curD, sbc, kwc);
  k_fineS <<<dim3(CC, RR), 1024, 0, stream>>>(sbc, gsb, degb);
  k_fineD <<<dim3(CC, RR), 1024, 0, stream>>>(kwc, gdb, degb, feat, kw4, gfin, invi, rw16, agg1);
  k_l1b   <<<(NN + 255) / 256, 256, 0, stream>>>(agg1, invi, W1, b1, h1h);
  k_l2    <<<NB, 256, 0, stream>>>(kw4, gfin, rw16, h1h, invi, W2, gid, pool, cnt);
  k_final <<<(BB + 255) / 256, 256, 0, stream>>>(pool, cnt, b2, Wc, bc, (float*)d_out);
}